// Round 5
// baseline (572.830 us; speedup 1.0000x reference)
//
#include <hip/hip_runtime.h>

// FourierFilter: per-(b,c) rfft-4096 -> top-k (80% energy) spectral mask -> irfft.
// x:[32,4096,128] f32. out = concat(x_var, x_inv), each [32,4096,128].
// SINGLE fused kernel: one 1024-thread block handles 4 ADJACENT channels of one batch
// (4 independent 256-thread FFT "groups" sharing the block's barriers). All global
// traffic is float4 (16B/lane): load x -> LDS, FFT/filter/iFFT in LDS, then re-read x
// (L3-resident: output stores are NON-TEMPORAL so they don't evict it) and write
// xvar / xinv = x - xvar with non-temporal stores.
// Selection: 4-pass weighted radix select (256-bin LDS histogram per group) — same
// tau = max t with S(t) > 0.8*total semantics as bit-bisection, ~8 barriers vs 32.
// XCD swizzle keeps the 4 blocks sharing each 64B x/out line dispatch-adjacent on one XCD.

#define TLEN 4096
#define N2   2048
#define CCH  128
#define BB   32
#define HALF 16777216  // 32*4096*128
#define PI_F 3.14159265358979323846f

// LDS pad swizzle for FFT arrays
#define LP(i) ((i) + ((i) >> 5))
#define ZLEN 2113      // LP(2048) + safety

// Native clang vector for nontemporal builtins (HIP_vector_type float4 is rejected).
typedef float fx4 __attribute__((ext_vector_type(4)));

__device__ __forceinline__ void cmul(float& r, float& i, float br, float bi) {
  float tr = r * br - i * bi;
  i = r * bi + i * br;
  r = tr;
}

__device__ __forceinline__ void dft4(float vr[4], float vi[4], float s) {
  float t0r = vr[0] + vr[2], t0i = vi[0] + vi[2];
  float t1r = vr[0] - vr[2], t1i = vi[0] - vi[2];
  float t2r = vr[1] + vr[3], t2i = vi[1] + vi[3];
  float d3r = vr[1] - vr[3], d3i = vi[1] - vi[3];
  float t3r = -s * d3i, t3i = s * d3r;
  vr[0] = t0r + t2r; vi[0] = t0i + t2i;
  vr[1] = t1r + t3r; vi[1] = t1i + t3i;
  vr[2] = t0r - t2r; vi[2] = t0i - t2i;
  vr[3] = t1r - t3r; vi[3] = t1i - t3i;
}

__device__ __forceinline__ void dft8(float vr[8], float vi[8], float s) {
  float er[4]  = {vr[0], vr[2], vr[4], vr[6]};
  float ei[4]  = {vi[0], vi[2], vi[4], vi[6]};
  float odr[4] = {vr[1], vr[3], vr[5], vr[7]};
  float odi[4] = {vi[1], vi[3], vi[5], vi[7]};
  dft4(er, ei, s);
  dft4(odr, odi, s);
  const float c = 0.70710678118654752440f;
  float wr[4] = {1.0f, c, 0.0f, -c};
  float wi[4] = {0.0f, s * c, s, s * c};
  #pragma unroll
  for (int k = 0; k < 4; ++k) {
    float tr = wr[k] * odr[k] - wi[k] * odi[k];
    float ti = wr[k] * odi[k] + wi[k] * odr[k];
    vr[k]     = er[k] + tr; vi[k]     = ei[k] + ti;
    vr[k + 4] = er[k] - tr; vi[k + 4] = ei[k] - ti;
  }
}

__device__ __forceinline__ void stage8_first(float* zr, float* zi, int tid, float s) {
  float vr[8], vi[8];
  #pragma unroll
  for (int r = 0; r < 8; ++r) {
    int idx = LP(tid + (r << 8));
    vr[r] = zr[idx]; vi[r] = zi[idx];
  }
  dft8(vr, vi, s);
  __syncthreads();
  #pragma unroll
  for (int r = 0; r < 8; ++r) {
    int idx = LP((tid << 3) + r);
    zr[idx] = vr[r]; zi[idx] = vi[r];
  }
  __syncthreads();
}

template <int NS>
__device__ __forceinline__ void stage8_tw(float* zr, float* zi, int tid, float s) {
  int j = tid;
  int p = j & (NS - 1);
  float vr[8], vi[8];
  #pragma unroll
  for (int r = 0; r < 8; ++r) {
    int idx = LP(j + (r << 8));
    vr[r] = zr[idx]; vi[r] = zi[idx];
  }
  float ang = s * 6.28318530717958647692f * (float)p / (float)(NS * 8);
  float s1, c1; __sincosf(ang, &s1, &c1);
  float c2 = c1 * c1 - s1 * s1, s2 = 2.0f * c1 * s1;
  float c3 = c2 * c1 - s2 * s1, s3 = c2 * s1 + s2 * c1;
  float c4 = c2 * c2 - s2 * s2, s4 = 2.0f * c2 * s2;
  float c5 = c4 * c1 - s4 * s1, s5 = c4 * s1 + s4 * c1;
  float c6 = c4 * c2 - s4 * s2, s6 = c4 * s2 + s4 * c2;
  float c7 = c4 * c3 - s4 * s3, s7 = c4 * s3 + s4 * c3;
  cmul(vr[1], vi[1], c1, s1);
  cmul(vr[2], vi[2], c2, s2);
  cmul(vr[3], vi[3], c3, s3);
  cmul(vr[4], vi[4], c4, s4);
  cmul(vr[5], vi[5], c5, s5);
  cmul(vr[6], vi[6], c6, s6);
  cmul(vr[7], vi[7], c7, s7);
  dft8(vr, vi, s);
  __syncthreads();
  int idxD = ((j - p) << 3) + p;
  #pragma unroll
  for (int r = 0; r < 8; ++r) {
    int idx = LP(idxD + r * NS);
    zr[idx] = vr[r]; zi[idx] = vi[r];
  }
  __syncthreads();
}

__device__ __forceinline__ void stage4_last(float* zr, float* zi, int tid, float s) {
  #pragma unroll
  for (int half = 0; half < 2; ++half) {
    int j = tid + (half << 8);
    float ang = s * PI_F * (float)j * (1.0f / 1024.0f);
    float s1, c1; __sincosf(ang, &s1, &c1);
    float c2 = c1 * c1 - s1 * s1, s2 = 2.0f * c1 * s1;
    float c3 = c2 * c1 - s2 * s1, s3 = c2 * s1 + s2 * c1;
    float vr[4], vi[4];
    #pragma unroll
    for (int r = 0; r < 4; ++r) {
      int idx = LP(j + (r << 9));
      vr[r] = zr[idx]; vi[r] = zi[idx];
    }
    cmul(vr[1], vi[1], c1, s1);
    cmul(vr[2], vi[2], c2, s2);
    cmul(vr[3], vi[3], c3, s3);
    dft4(vr, vi, s);
    #pragma unroll
    for (int r = 0; r < 4; ++r) {
      int idx = LP(j + (r << 9));
      zr[idx] = vr[r]; zi[idx] = vi[r];
    }
  }
  __syncthreads();
}

__device__ __forceinline__ void fft2048(float* zr, float* zi, int tid, float s) {
  stage8_first(zr, zi, tid, s);
  stage8_tw<8>(zr, zi, tid, s);
  stage8_tw<64>(zr, zi, tid, s);
  stage4_last(zr, zi, tid, s);
}

// Group-level (256-thread) reduction inside a 1024-thread block; all threads call it.
__device__ __forceinline__ float group_sum(float v, float* redg, int tg) {
  #pragma unroll
  for (int o = 32; o > 0; o >>= 1) v += __shfl_down(v, o, 64);
  if ((tg & 63) == 0) redg[tg >> 6] = v;
  __syncthreads();
  return redg[0] + redg[1] + redg[2] + redg[3];
}

// One 1024-thread block per (batch b, channel-quad cg): 4 independent FFT groups.
__global__ __launch_bounds__(1024, 8) void fourier_filter_fused(const float* __restrict__ x,
                                                                float* __restrict__ xvar,
                                                                float* __restrict__ xinv) {
  // z[0]=real planes, z[1]=imag planes; plane g = series for channel cbase+g.
  __shared__ float z[2][4][ZLEN];
  __shared__ float red[16];        // 4 floats per group
  __shared__ float hist[4][256];   // radix-select weighted histogram, per group
  __shared__ int   selD[4][8];     // chosen digit candidate per (group, wave-in-group)
  __shared__ float selS[4][8];     // wave suffix totals
  __shared__ float selB[4][8];     // strictly-above delta from candidate lane

  int tidx = threadIdx.x;

  // XCD swizzle: bid = m*8 + r round-robins r across XCDs. Decompose m so the 4
  // blocks sharing each 64B line (same b, same line-group, ql=0..3) are
  // m-consecutive on the same XCD r, and the line-group rotates with (r+b).
  int bid = blockIdx.x;
  int r = bid & 7;            // XCD under round-robin dispatch
  int m = bid >> 3;           // 0..127
  int b = m >> 2;             // 0..31
  int ql = m & 3;             // quad-within-line-group
  int cg = (((r + b) & 7) << 2) | ql;   // channel-quad 0..31
  int cbase = cg << 2;

  const float* xp = x + (size_t)b * (TLEN * CCH) + cbase;

  // ---- Load: thread covers time t; float4 spans the block's 4 channels. ----
  // (Do NOT hold x in registers across the FFTs: at 64-VGPR budget that spills —
  //  round-3 lesson, +176MB scratch write traffic. Re-read at store time instead;
  //  nt output stores keep x L3-resident so the re-read is an Infinity-Cache hit.)
  hist[tidx >> 8][tidx & 255] = 0.0f;   // zero radix histogram while loads fly
  #pragma unroll
  for (int it = 0; it < 4; ++it) {
    int t = tidx + (it << 10);
    fx4 v = *(const fx4*)(xp + (size_t)t * CCH);
    float* dst = &z[t & 1][0][0];       // parity -> real/imag plane (no branch)
    int k = LP(t >> 1);
    dst[k]            = v.x;
    dst[ZLEN + k]     = v.y;
    dst[2 * ZLEN + k] = v.z;
    dst[3 * ZLEN + k] = v.w;
  }
  __syncthreads();

  int g  = tidx >> 8;         // FFT group = channel within quad
  int tg = tidx & 255;        // thread-in-group
  int lane = tg & 63;         // lane within wave
  int w = tg >> 6;            // wave within group
  float* Zr = z[0][g];
  float* Zi = z[1][g];
  float* redg = red + (g << 2);

  fft2048(Zr, Zi, tg, -1.0f);   // forward

  // ---- Unpack to rfft bins X[0..2048] IN PLACE; energies in regs + pass-0 histogram. ----
  float eb[9];
  eb[8] = 0.0f;
  const float RC  = 0.92387953251128675613f;   // cos(pi/8)
  const float RSn = -0.38268343236508977173f;  // -sin(pi/8)
  float ws, wc;
  __sincosf(-PI_F * (float)tg * (1.0f / 2048.0f), &ws, &wc);
  #pragma unroll
  for (int jj = 0; jj < 4; ++jj) {
    int k = tg + (jj << 8);
    int mkz = (N2 - k) & (N2 - 1);
    int ik = LP(k), im = LP(N2 - k);
    float akr = Zr[ik],      aki = Zi[ik];
    float bkr = Zr[LP(mkz)], bki = Zi[LP(mkz)];
    float Er  = 0.5f * (akr + bkr);
    float Ei  = 0.5f * (aki - bki);
    float Or_ = 0.5f * (aki + bki);
    float Oi  = 0.5f * (bkr - akr);
    float tr = wc * Or_ - ws * Oi;
    float ti = wc * Oi + ws * Or_;
    float x0r = Er + tr, x0i = Ei + ti;
    float x1r = Er - tr, x1i = ti - Ei;
    Zr[ik] = x0r; Zi[ik] = x0i;
    Zr[im] = x1r; Zi[im] = x1i;
    float e0 = x0r * x0r + x0i * x0i;
    float e1 = x1r * x1r + x1i * x1i;
    eb[2 * jj]     = e0;
    eb[2 * jj + 1] = e1;
    atomicAdd(&hist[g][__float_as_uint(e0) >> 24], e0);
    atomicAdd(&hist[g][__float_as_uint(e1) >> 24], e1);
    float nwc = wc * RC - ws * RSn;
    ws = wc * RSn + ws * RC; wc = nwc;
  }
  if (tg == 0) {
    int i4 = LP(1024);
    float re = Zr[i4], im_ = Zi[i4];
    Zi[i4] = -im_;
    float e8 = re * re + im_ * im_;
    eb[8] = e8;
    atomicAdd(&hist[g][__float_as_uint(e8) >> 24], e8);
  }

  // ---- Total energy (group_sum's barrier also publishes pass-0 histogram). ----
  float tloc = 0.0f;
  #pragma unroll
  for (int s = 0; s < 9; ++s) tloc += eb[s];
  float total = group_sum(tloc, redg, tg);
  float thresh = 0.8f * total;

  // ---- 4-pass weighted radix select: tau = max t with sum(e >= t) > thresh. ----
  unsigned prefix = 0u;
  float s_above = 0.0f;
  #pragma unroll
  for (int pass = 0; pass < 4; ++pass) {
    int shift = 24 - (pass << 3);
    if (pass > 0) {
      unsigned hm = 0xFFFFFFFFu << (shift + 8);
      #pragma unroll
      for (int s = 0; s < 9; ++s) {
        unsigned bits = __float_as_uint(eb[s]);
        if ((bits & hm) == prefix)
          atomicAdd(&hist[g][(bits >> shift) & 255u], eb[s]);
      }
      __syncthreads();   // build complete
    }
    // Read own bin, pre-zero for next pass, wave suffix-scan.
    float h = hist[g][tg];
    hist[g][tg] = 0.0f;
    float sfx = h;
    #pragma unroll
    for (int o = 1; o < 64; o <<= 1) {
      float t2 = __shfl_down(sfx, o, 64);
      sfx += (lane + o < 64) ? t2 : 0.0f;
    }
    if (lane == 0) selS[g][w] = sfx;   // wave total
    __syncthreads();
    float addw = 0.0f;
    #pragma unroll
    for (int w2 = 1; w2 < 4; ++w2) addw += (w + w2 < 4) ? selS[g][w + w2] : 0.0f;
    sfx += addw;
    bool pred = (s_above + sfx > thresh);      // monotone non-increasing in tg
    unsigned long long mk = __ballot(pred);
    if (mk != 0ull) {
      if (lane == 63 - __clzll(mk)) { selD[g][w] = tg; selB[g][w] = sfx - h; }
    } else if (lane == 0) {
      selD[g][w] = -1;
    }
    __syncthreads();
    int D = -1; float delta = 0.0f;
    if (selD[g][3] >= 0)      { D = selD[g][3]; delta = selB[g][3]; }
    else if (selD[g][2] >= 0) { D = selD[g][2]; delta = selB[g][2]; }
    else if (selD[g][1] >= 0) { D = selD[g][1]; delta = selB[g][1]; }
    else if (selD[g][0] >= 0) { D = selD[g][0]; delta = selB[g][0]; }
    if (D < 0) { D = 0; delta = 0.0f; }        // degenerate all-zero safeguard
    s_above += delta;
    prefix |= ((unsigned)D) << shift;
  }
  float tau = __uint_as_float(prefix);

  // ---- Mask + hermitian repack IN PLACE. ----
  const float RSp = 0.38268343236508977173f;
  __sincosf(PI_F * (float)tg * (1.0f / 2048.0f), &ws, &wc);
  #pragma unroll
  for (int jj = 0; jj < 4; ++jj) {
    int k = tg + (jj << 8);
    int ik = LP(k), im = LP(N2 - k);
    float xkr = Zr[ik], xki = Zi[ik];
    float xmr = Zr[im], xmi = Zi[im];
    float ekk = xkr * xkr + xki * xki;
    float emm = xmr * xmr + xmi * xmi;
    if (ekk >= tau) { xkr = 0.0f; xki = 0.0f; }
    if (emm >= tau) { xmr = 0.0f; xmi = 0.0f; }
    float Er = 0.5f * (xkr + xmr);
    float Ei = 0.5f * (xki - xmi);
    float Br = 0.5f * (xkr - xmr);
    float Bi = 0.5f * (xki + xmi);
    float Or_ = wc * Br - ws * Bi;
    float Oi  = wc * Bi + ws * Br;
    Zr[ik] = Er - Oi;  Zi[ik] = Ei + Or_;
    Zr[im] = Er + Oi;  Zi[im] = Or_ - Ei;
    float nwc = wc * RC - ws * RSp;
    ws = wc * RSp + ws * RC; wc = nwc;
  }
  if (tg == 0) {
    int i4 = LP(1024);
    float re = Zr[i4], im_ = Zi[i4];
    float e = re * re + im_ * im_;
    if (e >= tau) { re = 0.0f; im_ = 0.0f; }
    Zr[i4] = re; Zi[i4] = -im_;
  }
  __syncthreads();

  fft2048(Zr, Zi, tg, 1.0f);    // inverse (unscaled); ends with __syncthreads()

  // ---- Store: xvar float4 across the 4 channels; xinv = x - xvar. ----
  // x re-read hits Infinity Cache (nt stores below don't evict it); outputs are
  // write-once -> non-temporal stores (no L2/L3 allocate, no x eviction).
  const float scale = 1.0f / 2048.0f;
  size_t base = (size_t)b * (TLEN * CCH) + cbase;
  #pragma unroll
  for (int it = 0; it < 4; ++it) {
    int t = tidx + (it << 10);
    const float* src = &z[t & 1][0][0];
    int k = LP(t >> 1);
    fx4 v;
    v.x = src[k]            * scale;
    v.y = src[ZLEN + k]     * scale;
    v.z = src[2 * ZLEN + k] * scale;
    v.w = src[3 * ZLEN + k] * scale;
    size_t off = base + (size_t)t * CCH;
    fx4 xv = __builtin_nontemporal_load((const fx4*)(x + off));
    fx4 d;
    d.x = xv.x - v.x; d.y = xv.y - v.y; d.z = xv.z - v.z; d.w = xv.w - v.w;
    __builtin_nontemporal_store(v, (fx4*)(xvar + off));
    __builtin_nontemporal_store(d, (fx4*)(xinv + off));
  }
}

extern "C" void kernel_launch(void* const* d_in, const int* in_sizes, int n_in,
                              void* d_out, int out_size, void* d_ws, size_t ws_size,
                              hipStream_t stream) {
  const float* x = (const float*)d_in[0];
  float* out  = (float*)d_out;
  float* xvar = out;
  float* xinv = out + HALF;

  (void)d_ws; (void)ws_size;
  fourier_filter_fused<<<BB * 32, 1024, 0, stream>>>(x, xvar, xinv);
}

// Round 6
// 340.938 us; speedup vs baseline: 1.6802x; 1.6802x over previous
//
#include <hip/hip_runtime.h>

// FourierFilter: per-(b,c) rfft-4096 -> top-k (80% energy) spectral mask -> irfft.
// x:[32,4096,128] f32. out = concat(x_var, x_inv), each [32,4096,128].
// SINGLE fused kernel: one 1024-thread block handles 4 ADJACENT channels of one batch
// (4 independent 256-thread FFT "groups" sharing the block's barriers). All global
// traffic is float4 (16B/lane), CACHED (L2 write-combines the 4 blocks' partial-line
// stores; round-5 lesson: nt stores break combining -> RMW, 2x write traffic).
// Load x -> LDS, FFT/filter/iFFT in LDS, re-read x at store time, write xvar / xinv.
// Selection: 4-pass weighted radix select (256-bin LDS histogram per group) — same
// tau = max t with S(t) > 0.8*total semantics as bit-bisection, ~8 barriers vs 32.
// XCD swizzle keeps the 4 blocks sharing each 64B x/out line dispatch-adjacent on one XCD.

#define TLEN 4096
#define N2   2048
#define CCH  128
#define BB   32
#define HALF 16777216  // 32*4096*128
#define PI_F 3.14159265358979323846f

// LDS pad swizzle for FFT arrays
#define LP(i) ((i) + ((i) >> 5))
#define ZLEN 2113      // LP(2048) + safety

__device__ __forceinline__ void cmul(float& r, float& i, float br, float bi) {
  float tr = r * br - i * bi;
  i = r * bi + i * br;
  r = tr;
}

__device__ __forceinline__ void dft4(float vr[4], float vi[4], float s) {
  float t0r = vr[0] + vr[2], t0i = vi[0] + vi[2];
  float t1r = vr[0] - vr[2], t1i = vi[0] - vi[2];
  float t2r = vr[1] + vr[3], t2i = vi[1] + vi[3];
  float d3r = vr[1] - vr[3], d3i = vi[1] - vi[3];
  float t3r = -s * d3i, t3i = s * d3r;
  vr[0] = t0r + t2r; vi[0] = t0i + t2i;
  vr[1] = t1r + t3r; vi[1] = t1i + t3i;
  vr[2] = t0r - t2r; vi[2] = t0i - t2i;
  vr[3] = t1r - t3r; vi[3] = t1i - t3i;
}

__device__ __forceinline__ void dft8(float vr[8], float vi[8], float s) {
  float er[4]  = {vr[0], vr[2], vr[4], vr[6]};
  float ei[4]  = {vi[0], vi[2], vi[4], vi[6]};
  float odr[4] = {vr[1], vr[3], vr[5], vr[7]};
  float odi[4] = {vi[1], vi[3], vi[5], vi[7]};
  dft4(er, ei, s);
  dft4(odr, odi, s);
  const float c = 0.70710678118654752440f;
  float wr[4] = {1.0f, c, 0.0f, -c};
  float wi[4] = {0.0f, s * c, s, s * c};
  #pragma unroll
  for (int k = 0; k < 4; ++k) {
    float tr = wr[k] * odr[k] - wi[k] * odi[k];
    float ti = wr[k] * odi[k] + wi[k] * odr[k];
    vr[k]     = er[k] + tr; vi[k]     = ei[k] + ti;
    vr[k + 4] = er[k] - tr; vi[k + 4] = ei[k] - ti;
  }
}

__device__ __forceinline__ void stage8_first(float* zr, float* zi, int tid, float s) {
  float vr[8], vi[8];
  #pragma unroll
  for (int r = 0; r < 8; ++r) {
    int idx = LP(tid + (r << 8));
    vr[r] = zr[idx]; vi[r] = zi[idx];
  }
  dft8(vr, vi, s);
  __syncthreads();
  #pragma unroll
  for (int r = 0; r < 8; ++r) {
    int idx = LP((tid << 3) + r);
    zr[idx] = vr[r]; zi[idx] = vi[r];
  }
  __syncthreads();
}

template <int NS>
__device__ __forceinline__ void stage8_tw(float* zr, float* zi, int tid, float s) {
  int j = tid;
  int p = j & (NS - 1);
  float vr[8], vi[8];
  #pragma unroll
  for (int r = 0; r < 8; ++r) {
    int idx = LP(j + (r << 8));
    vr[r] = zr[idx]; vi[r] = zi[idx];
  }
  float ang = s * 6.28318530717958647692f * (float)p / (float)(NS * 8);
  float s1, c1; __sincosf(ang, &s1, &c1);
  float c2 = c1 * c1 - s1 * s1, s2 = 2.0f * c1 * s1;
  float c3 = c2 * c1 - s2 * s1, s3 = c2 * s1 + s2 * c1;
  float c4 = c2 * c2 - s2 * s2, s4 = 2.0f * c2 * s2;
  float c5 = c4 * c1 - s4 * s1, s5 = c4 * s1 + s4 * c1;
  float c6 = c4 * c2 - s4 * s2, s6 = c4 * s2 + s4 * c2;
  float c7 = c4 * c3 - s4 * s3, s7 = c4 * s3 + s4 * c3;
  cmul(vr[1], vi[1], c1, s1);
  cmul(vr[2], vi[2], c2, s2);
  cmul(vr[3], vi[3], c3, s3);
  cmul(vr[4], vi[4], c4, s4);
  cmul(vr[5], vi[5], c5, s5);
  cmul(vr[6], vi[6], c6, s6);
  cmul(vr[7], vi[7], c7, s7);
  dft8(vr, vi, s);
  __syncthreads();
  int idxD = ((j - p) << 3) + p;
  #pragma unroll
  for (int r = 0; r < 8; ++r) {
    int idx = LP(idxD + r * NS);
    zr[idx] = vr[r]; zi[idx] = vi[r];
  }
  __syncthreads();
}

__device__ __forceinline__ void stage4_last(float* zr, float* zi, int tid, float s) {
  #pragma unroll
  for (int half = 0; half < 2; ++half) {
    int j = tid + (half << 8);
    float ang = s * PI_F * (float)j * (1.0f / 1024.0f);
    float s1, c1; __sincosf(ang, &s1, &c1);
    float c2 = c1 * c1 - s1 * s1, s2 = 2.0f * c1 * s1;
    float c3 = c2 * c1 - s2 * s1, s3 = c2 * s1 + s2 * c1;
    float vr[4], vi[4];
    #pragma unroll
    for (int r = 0; r < 4; ++r) {
      int idx = LP(j + (r << 9));
      vr[r] = zr[idx]; vi[r] = zi[idx];
    }
    cmul(vr[1], vi[1], c1, s1);
    cmul(vr[2], vi[2], c2, s2);
    cmul(vr[3], vi[3], c3, s3);
    dft4(vr, vi, s);
    #pragma unroll
    for (int r = 0; r < 4; ++r) {
      int idx = LP(j + (r << 9));
      zr[idx] = vr[r]; zi[idx] = vi[r];
    }
  }
  __syncthreads();
}

__device__ __forceinline__ void fft2048(float* zr, float* zi, int tid, float s) {
  stage8_first(zr, zi, tid, s);
  stage8_tw<8>(zr, zi, tid, s);
  stage8_tw<64>(zr, zi, tid, s);
  stage4_last(zr, zi, tid, s);
}

// Group-level (256-thread) reduction inside a 1024-thread block; all threads call it.
__device__ __forceinline__ float group_sum(float v, float* redg, int tg) {
  #pragma unroll
  for (int o = 32; o > 0; o >>= 1) v += __shfl_down(v, o, 64);
  if ((tg & 63) == 0) redg[tg >> 6] = v;
  __syncthreads();
  return redg[0] + redg[1] + redg[2] + redg[3];
}

// One 1024-thread block per (batch b, channel-quad cg): 4 independent FFT groups.
__global__ __launch_bounds__(1024, 8) void fourier_filter_fused(const float* __restrict__ x,
                                                                float* __restrict__ xvar,
                                                                float* __restrict__ xinv) {
  // z[0]=real planes, z[1]=imag planes; plane g = series for channel cbase+g.
  __shared__ float z[2][4][ZLEN];
  __shared__ float red[16];        // 4 floats per group
  __shared__ float hist[4][256];   // radix-select weighted histogram, per group
  __shared__ int   selD[4][8];     // chosen digit candidate per (group, wave-in-group)
  __shared__ float selS[4][8];     // wave suffix totals
  __shared__ float selB[4][8];     // strictly-above delta from candidate lane

  int tidx = threadIdx.x;

  // XCD swizzle: bid = m*8 + r round-robins r across XCDs. Decompose m so the 4
  // blocks sharing each 64B line (same b, same line-group, ql=0..3) are
  // m-consecutive on the same XCD r, and the line-group rotates with (r+b).
  int bid = blockIdx.x;
  int r = bid & 7;            // XCD under round-robin dispatch
  int m = bid >> 3;           // 0..127
  int b = m >> 2;             // 0..31
  int ql = m & 3;             // quad-within-line-group
  int cg = (((r + b) & 7) << 2) | ql;   // channel-quad 0..31
  int cbase = cg << 2;

  const float* xp = x + (size_t)b * (TLEN * CCH) + cbase;

  // ---- Load: thread covers time t; float4 spans the block's 4 channels. ----
  // (Do NOT hold x in registers across the FFTs: at 64-VGPR budget that spills —
  //  round-3 lesson, +176MB scratch traffic. Re-read at store time instead.)
  hist[tidx >> 8][tidx & 255] = 0.0f;   // zero radix histogram while loads fly
  #pragma unroll
  for (int it = 0; it < 4; ++it) {
    int t = tidx + (it << 10);
    float4 v = *(const float4*)(xp + (size_t)t * CCH);
    float* dst = &z[t & 1][0][0];       // parity -> real/imag plane (no branch)
    int k = LP(t >> 1);
    dst[k]            = v.x;
    dst[ZLEN + k]     = v.y;
    dst[2 * ZLEN + k] = v.z;
    dst[3 * ZLEN + k] = v.w;
  }
  __syncthreads();

  int g  = tidx >> 8;         // FFT group = channel within quad
  int tg = tidx & 255;        // thread-in-group
  int lane = tg & 63;         // lane within wave
  int w = tg >> 6;            // wave within group
  float* Zr = z[0][g];
  float* Zi = z[1][g];
  float* redg = red + (g << 2);

  fft2048(Zr, Zi, tg, -1.0f);   // forward

  // ---- Unpack to rfft bins X[0..2048] IN PLACE; energies in regs + pass-0 histogram. ----
  float eb[9];
  eb[8] = 0.0f;
  const float RC  = 0.92387953251128675613f;   // cos(pi/8)
  const float RSn = -0.38268343236508977173f;  // -sin(pi/8)
  float ws, wc;
  __sincosf(-PI_F * (float)tg * (1.0f / 2048.0f), &ws, &wc);
  #pragma unroll
  for (int jj = 0; jj < 4; ++jj) {
    int k = tg + (jj << 8);
    int mkz = (N2 - k) & (N2 - 1);
    int ik = LP(k), im = LP(N2 - k);
    float akr = Zr[ik],      aki = Zi[ik];
    float bkr = Zr[LP(mkz)], bki = Zi[LP(mkz)];
    float Er  = 0.5f * (akr + bkr);
    float Ei  = 0.5f * (aki - bki);
    float Or_ = 0.5f * (aki + bki);
    float Oi  = 0.5f * (bkr - akr);
    float tr = wc * Or_ - ws * Oi;
    float ti = wc * Oi + ws * Or_;
    float x0r = Er + tr, x0i = Ei + ti;
    float x1r = Er - tr, x1i = ti - Ei;
    Zr[ik] = x0r; Zi[ik] = x0i;
    Zr[im] = x1r; Zi[im] = x1i;
    float e0 = x0r * x0r + x0i * x0i;
    float e1 = x1r * x1r + x1i * x1i;
    eb[2 * jj]     = e0;
    eb[2 * jj + 1] = e1;
    atomicAdd(&hist[g][__float_as_uint(e0) >> 24], e0);
    atomicAdd(&hist[g][__float_as_uint(e1) >> 24], e1);
    float nwc = wc * RC - ws * RSn;
    ws = wc * RSn + ws * RC; wc = nwc;
  }
  if (tg == 0) {
    int i4 = LP(1024);
    float re = Zr[i4], im_ = Zi[i4];
    Zi[i4] = -im_;
    float e8 = re * re + im_ * im_;
    eb[8] = e8;
    atomicAdd(&hist[g][__float_as_uint(e8) >> 24], e8);
  }

  // ---- Total energy (group_sum's barrier also publishes pass-0 histogram). ----
  float tloc = 0.0f;
  #pragma unroll
  for (int s = 0; s < 9; ++s) tloc += eb[s];
  float total = group_sum(tloc, redg, tg);
  float thresh = 0.8f * total;

  // ---- 4-pass weighted radix select: tau = max t with sum(e >= t) > thresh. ----
  unsigned prefix = 0u;
  float s_above = 0.0f;
  #pragma unroll
  for (int pass = 0; pass < 4; ++pass) {
    int shift = 24 - (pass << 3);
    if (pass > 0) {
      unsigned hm = 0xFFFFFFFFu << (shift + 8);
      #pragma unroll
      for (int s = 0; s < 9; ++s) {
        unsigned bits = __float_as_uint(eb[s]);
        if ((bits & hm) == prefix)
          atomicAdd(&hist[g][(bits >> shift) & 255u], eb[s]);
      }
      __syncthreads();   // build complete
    }
    // Read own bin, pre-zero for next pass, wave suffix-scan.
    float h = hist[g][tg];
    hist[g][tg] = 0.0f;
    float sfx = h;
    #pragma unroll
    for (int o = 1; o < 64; o <<= 1) {
      float t2 = __shfl_down(sfx, o, 64);
      sfx += (lane + o < 64) ? t2 : 0.0f;
    }
    if (lane == 0) selS[g][w] = sfx;   // wave total
    __syncthreads();
    float addw = 0.0f;
    #pragma unroll
    for (int w2 = 1; w2 < 4; ++w2) addw += (w + w2 < 4) ? selS[g][w + w2] : 0.0f;
    sfx += addw;
    bool pred = (s_above + sfx > thresh);      // monotone non-increasing in tg
    unsigned long long mk = __ballot(pred);
    if (mk != 0ull) {
      if (lane == 63 - __clzll(mk)) { selD[g][w] = tg; selB[g][w] = sfx - h; }
    } else if (lane == 0) {
      selD[g][w] = -1;
    }
    __syncthreads();
    int D = -1; float delta = 0.0f;
    if (selD[g][3] >= 0)      { D = selD[g][3]; delta = selB[g][3]; }
    else if (selD[g][2] >= 0) { D = selD[g][2]; delta = selB[g][2]; }
    else if (selD[g][1] >= 0) { D = selD[g][1]; delta = selB[g][1]; }
    else if (selD[g][0] >= 0) { D = selD[g][0]; delta = selB[g][0]; }
    if (D < 0) { D = 0; delta = 0.0f; }        // degenerate all-zero safeguard
    s_above += delta;
    prefix |= ((unsigned)D) << shift;
  }
  float tau = __uint_as_float(prefix);

  // ---- Mask + hermitian repack IN PLACE. ----
  const float RSp = 0.38268343236508977173f;
  __sincosf(PI_F * (float)tg * (1.0f / 2048.0f), &ws, &wc);
  #pragma unroll
  for (int jj = 0; jj < 4; ++jj) {
    int k = tg + (jj << 8);
    int ik = LP(k), im = LP(N2 - k);
    float xkr = Zr[ik], xki = Zi[ik];
    float xmr = Zr[im], xmi = Zi[im];
    float ekk = xkr * xkr + xki * xki;
    float emm = xmr * xmr + xmi * xmi;
    if (ekk >= tau) { xkr = 0.0f; xki = 0.0f; }
    if (emm >= tau) { xmr = 0.0f; xmi = 0.0f; }
    float Er = 0.5f * (xkr + xmr);
    float Ei = 0.5f * (xki - xmi);
    float Br = 0.5f * (xkr - xmr);
    float Bi = 0.5f * (xki + xmi);
    float Or_ = wc * Br - ws * Bi;
    float Oi  = wc * Bi + ws * Br;
    Zr[ik] = Er - Oi;  Zi[ik] = Ei + Or_;
    Zr[im] = Er + Oi;  Zi[im] = Or_ - Ei;
    float nwc = wc * RC - ws * RSp;
    ws = wc * RSp + ws * RC; wc = nwc;
  }
  if (tg == 0) {
    int i4 = LP(1024);
    float re = Zr[i4], im_ = Zi[i4];
    float e = re * re + im_ * im_;
    if (e >= tau) { re = 0.0f; im_ = 0.0f; }
    Zr[i4] = re; Zi[i4] = -im_;
  }
  __syncthreads();

  fft2048(Zr, Zi, tg, 1.0f);    // inverse (unscaled); ends with __syncthreads()

  // ---- Store: xvar float4 across the 4 channels; xinv = x - xvar. ----
  // CACHED loads/stores: L2 write-combines the 4 quads' partial-line stores
  // (round-5 lesson: nt here = RMW amplification, 2x writes, +128MB fetches).
  const float scale = 1.0f / 2048.0f;
  size_t base = (size_t)b * (TLEN * CCH) + cbase;
  #pragma unroll
  for (int it = 0; it < 4; ++it) {
    int t = tidx + (it << 10);
    const float* src = &z[t & 1][0][0];
    int k = LP(t >> 1);
    float4 v;
    v.x = src[k]            * scale;
    v.y = src[ZLEN + k]     * scale;
    v.z = src[2 * ZLEN + k] * scale;
    v.w = src[3 * ZLEN + k] * scale;
    size_t off = base + (size_t)t * CCH;
    float4 xv = *(const float4*)(x + off);
    *(float4*)(xvar + off) = v;
    *(float4*)(xinv + off) = make_float4(xv.x - v.x, xv.y - v.y, xv.z - v.z, xv.w - v.w);
  }
}

extern "C" void kernel_launch(void* const* d_in, const int* in_sizes, int n_in,
                              void* d_out, int out_size, void* d_ws, size_t ws_size,
                              hipStream_t stream) {
  const float* x = (const float*)d_in[0];
  float* out  = (float*)d_out;
  float* xvar = out;
  float* xinv = out + HALF;

  (void)d_ws; (void)ws_size;
  fourier_filter_fused<<<BB * 32, 1024, 0, stream>>>(x, xvar, xinv);
}

// Round 7
// 337.693 us; speedup vs baseline: 1.6963x; 1.0096x over previous
//
#include <hip/hip_runtime.h>

// FourierFilter: per-(b,c) rfft-4096 -> top-k (80% energy) spectral mask -> irfft.
// x:[32,4096,128] f32. out = concat(x_var, x_inv), each [32,4096,128].
// SINGLE fused kernel: one 1024-thread block handles 4 ADJACENT channels of one batch
// (4 independent 256-thread FFT "groups" sharing the block's barriers). All global
// traffic is float4 (16B/lane), CACHED (L2 write-combines the 4 sibling blocks'
// partial-line stores; round-5 lesson: nt stores break combining -> RMW, 2x writes).
// Selection: 31-iter bit bisection (constant-time; round-6 lesson: radix-select's
// LDS-atomic hot bins + data-dependent timing cost 40us and broke write-combining).
// NEW: twiddle tables in d_ws (21KB, init kernel, L1-resident) replace per-stage
// __sincosf + twiddle-power chains (~30% of core VALU ops).
// XCD swizzle keeps the 4 blocks sharing each 64B x/out line dispatch-adjacent on one XCD.

#define TLEN 4096
#define N2   2048
#define CCH  128
#define BB   32
#define HALF 16777216  // 32*4096*128
#define PI_F 3.14159265358979323846f

// LDS pad swizzle for FFT arrays
#define LP(i) ((i) + ((i) >> 5))
#define ZLEN 2113      // LP(2048) + safety

// Twiddle table layout in d_ws (float2 units):
//   [0,64)          stage8_tw<8>  : entry p*8+r = (cos,sin)(2*pi*p*r/64),  p<8, r<8
//   [64,576)        stage8_tw<64> : entry 64 + p*8+r = (cos,sin)(2*pi*p*r/512), p<64
//   [576,2624)      stage4_last   : entry 576 + j*4+r = (cos,sin)(pi*j*r/1024), j<512, r<4
#define TW_COUNT 2624
#define TW_O64   64
#define TW_O4    576

__device__ __forceinline__ void cmul(float& r, float& i, float br, float bi) {
  float tr = r * br - i * bi;
  i = r * bi + i * br;
  r = tr;
}

__device__ __forceinline__ void dft4(float vr[4], float vi[4], float s) {
  float t0r = vr[0] + vr[2], t0i = vi[0] + vi[2];
  float t1r = vr[0] - vr[2], t1i = vi[0] - vi[2];
  float t2r = vr[1] + vr[3], t2i = vi[1] + vi[3];
  float d3r = vr[1] - vr[3], d3i = vi[1] - vi[3];
  float t3r = -s * d3i, t3i = s * d3r;
  vr[0] = t0r + t2r; vi[0] = t0i + t2i;
  vr[1] = t1r + t3r; vi[1] = t1i + t3i;
  vr[2] = t0r - t2r; vi[2] = t0i - t2i;
  vr[3] = t1r - t3r; vi[3] = t1i - t3i;
}

__device__ __forceinline__ void dft8(float vr[8], float vi[8], float s) {
  float er[4]  = {vr[0], vr[2], vr[4], vr[6]};
  float ei[4]  = {vi[0], vi[2], vi[4], vi[6]};
  float odr[4] = {vr[1], vr[3], vr[5], vr[7]};
  float odi[4] = {vi[1], vi[3], vi[5], vi[7]};
  dft4(er, ei, s);
  dft4(odr, odi, s);
  const float c = 0.70710678118654752440f;
  float wr[4] = {1.0f, c, 0.0f, -c};
  float wi[4] = {0.0f, s * c, s, s * c};
  #pragma unroll
  for (int k = 0; k < 4; ++k) {
    float tr = wr[k] * odr[k] - wi[k] * odi[k];
    float ti = wr[k] * odi[k] + wi[k] * odr[k];
    vr[k]     = er[k] + tr; vi[k]     = ei[k] + ti;
    vr[k + 4] = er[k] - tr; vi[k + 4] = ei[k] - ti;
  }
}

__device__ __forceinline__ void stage8_first(float* zr, float* zi, int tid, float s) {
  float vr[8], vi[8];
  #pragma unroll
  for (int r = 0; r < 8; ++r) {
    int idx = LP(tid + (r << 8));
    vr[r] = zr[idx]; vi[r] = zi[idx];
  }
  dft8(vr, vi, s);
  __syncthreads();
  #pragma unroll
  for (int r = 0; r < 8; ++r) {
    int idx = LP((tid << 3) + r);
    zr[idx] = vr[r]; zi[idx] = vi[r];
  }
  __syncthreads();
}

template <int NS, bool TAB>
__device__ __forceinline__ void stage8_tw(float* zr, float* zi, int tid, float s,
                                          const float2* __restrict__ tab) {
  int j = tid;
  int p = j & (NS - 1);
  // Issue twiddle loads FIRST (L1-hot) so they overlap the LDS reads.
  float twc[7], tws[7];
  if (TAB) {
    const float2* t = tab + ((NS == 8) ? 0 : TW_O64) + (p << 3);
    #pragma unroll
    for (int r = 1; r < 8; ++r) {
      float2 wv = t[r];
      twc[r - 1] = wv.x; tws[r - 1] = s * wv.y;
    }
  }
  float vr[8], vi[8];
  #pragma unroll
  for (int r = 0; r < 8; ++r) {
    int idx = LP(j + (r << 8));
    vr[r] = zr[idx]; vi[r] = zi[idx];
  }
  if (!TAB) {
    float ang = s * 6.28318530717958647692f * (float)p / (float)(NS * 8);
    float s1, c1; __sincosf(ang, &s1, &c1);
    float c2 = c1 * c1 - s1 * s1, s2 = 2.0f * c1 * s1;
    float c3 = c2 * c1 - s2 * s1, s3 = c2 * s1 + s2 * c1;
    float c4 = c2 * c2 - s2 * s2, s4 = 2.0f * c2 * s2;
    float c5 = c4 * c1 - s4 * s1, s5 = c4 * s1 + s4 * c1;
    float c6 = c4 * c2 - s4 * s2, s6 = c4 * s2 + s4 * c2;
    float c7 = c4 * c3 - s4 * s3, s7 = c4 * s3 + s4 * c3;
    twc[0] = c1; tws[0] = s1; twc[1] = c2; tws[1] = s2;
    twc[2] = c3; tws[2] = s3; twc[3] = c4; tws[3] = s4;
    twc[4] = c5; tws[4] = s5; twc[5] = c6; tws[5] = s6;
    twc[6] = c7; tws[6] = s7;
  }
  #pragma unroll
  for (int r = 1; r < 8; ++r) cmul(vr[r], vi[r], twc[r - 1], tws[r - 1]);
  dft8(vr, vi, s);
  __syncthreads();
  int idxD = ((j - p) << 3) + p;
  #pragma unroll
  for (int r = 0; r < 8; ++r) {
    int idx = LP(idxD + r * NS);
    zr[idx] = vr[r]; zi[idx] = vi[r];
  }
  __syncthreads();
}

template <bool TAB>
__device__ __forceinline__ void stage4_last(float* zr, float* zi, int tid, float s,
                                            const float2* __restrict__ tab) {
  #pragma unroll
  for (int half = 0; half < 2; ++half) {
    int j = tid + (half << 8);
    float c1, s1, c2, s2, c3, s3;
    if (TAB) {
      const float2* t = tab + TW_O4 + (j << 2);
      float2 w1 = t[1], w2 = t[2], w3 = t[3];
      c1 = w1.x; s1 = s * w1.y;
      c2 = w2.x; s2 = s * w2.y;
      c3 = w3.x; s3 = s * w3.y;
    } else {
      float ang = s * PI_F * (float)j * (1.0f / 1024.0f);
      __sincosf(ang, &s1, &c1);
      c2 = c1 * c1 - s1 * s1; s2 = 2.0f * c1 * s1;
      c3 = c2 * c1 - s2 * s1; s3 = c2 * s1 + s2 * c1;
    }
    float vr[4], vi[4];
    #pragma unroll
    for (int r = 0; r < 4; ++r) {
      int idx = LP(j + (r << 9));
      vr[r] = zr[idx]; vi[r] = zi[idx];
    }
    cmul(vr[1], vi[1], c1, s1);
    cmul(vr[2], vi[2], c2, s2);
    cmul(vr[3], vi[3], c3, s3);
    dft4(vr, vi, s);
    #pragma unroll
    for (int r = 0; r < 4; ++r) {
      int idx = LP(j + (r << 9));
      zr[idx] = vr[r]; zi[idx] = vi[r];
    }
  }
  __syncthreads();
}

template <bool TAB>
__device__ __forceinline__ void fft2048(float* zr, float* zi, int tid, float s,
                                        const float2* __restrict__ tab) {
  stage8_first(zr, zi, tid, s);
  stage8_tw<8, TAB>(zr, zi, tid, s, tab);
  stage8_tw<64, TAB>(zr, zi, tid, s, tab);
  stage4_last<TAB>(zr, zi, tid, s, tab);
}

// Group-level (256-thread) reduction inside a 1024-thread block; all threads call it.
__device__ __forceinline__ float group_sum(float v, float* redg, int tg, int bank) {
  #pragma unroll
  for (int o = 32; o > 0; o >>= 1) v += __shfl_down(v, o, 64);
  if ((tg & 63) == 0) redg[(bank << 2) + (tg >> 6)] = v;
  __syncthreads();
  int b4 = bank << 2;
  return redg[b4] + redg[b4 + 1] + redg[b4 + 2] + redg[b4 + 3];
}

// One 1024-thread block per (batch b, channel-quad cg): 4 independent FFT groups.
template <bool TAB>
__global__ __launch_bounds__(1024, 8) void fourier_filter_fused(const float* __restrict__ x,
                                                                float* __restrict__ xvar,
                                                                float* __restrict__ xinv,
                                                                const float2* __restrict__ tab) {
  // z[0]=real planes, z[1]=imag planes; plane g = series for channel cbase+g.
  __shared__ float z[2][4][ZLEN];
  __shared__ float red[64];   // 8 floats per group (2 banks x 4 waves), 4 groups

  int tidx = threadIdx.x;

  // XCD swizzle: bid = m*8 + r round-robins r across XCDs. Decompose m so the 4
  // blocks sharing each 64B line (same b, same line-group, ql=0..3) are
  // m-consecutive on the same XCD r, and the line-group rotates with (r+b).
  int bid = blockIdx.x;
  int r = bid & 7;            // XCD under round-robin dispatch
  int m = bid >> 3;           // 0..127
  int b = m >> 2;             // 0..31
  int ql = m & 3;             // quad-within-line-group
  int cg = (((r + b) & 7) << 2) | ql;   // channel-quad 0..31
  int cbase = cg << 2;

  const float* xp = x + (size_t)b * (TLEN * CCH) + cbase;

  // ---- Load: thread covers time t; float4 spans the block's 4 channels. ----
  // (Do NOT hold x in registers across the FFTs: at this register budget that spills —
  //  round-3 lesson, +176MB scratch traffic. Re-read at store time instead.)
  #pragma unroll
  for (int it = 0; it < 4; ++it) {
    int t = tidx + (it << 10);
    float4 v = *(const float4*)(xp + (size_t)t * CCH);
    float* dst = &z[t & 1][0][0];       // parity -> real/imag plane (no branch)
    int k = LP(t >> 1);
    dst[k]            = v.x;
    dst[ZLEN + k]     = v.y;
    dst[2 * ZLEN + k] = v.z;
    dst[3 * ZLEN + k] = v.w;
  }
  __syncthreads();

  int g  = tidx >> 8;         // FFT group = channel within quad
  int tg = tidx & 255;        // thread-in-group
  float* Zr = z[0][g];
  float* Zi = z[1][g];
  float* redg = red + (g << 3);

  fft2048<TAB>(Zr, Zi, tg, -1.0f, tab);   // forward

  // ---- Unpack to rfft bins X[0..2048] IN PLACE; energies in regs. ----
  float eb[9];
  eb[8] = 0.0f;
  const float RC  = 0.92387953251128675613f;   // cos(pi/8)
  const float RSn = -0.38268343236508977173f;  // -sin(pi/8)
  float ws, wc;
  __sincosf(-PI_F * (float)tg * (1.0f / 2048.0f), &ws, &wc);
  #pragma unroll
  for (int jj = 0; jj < 4; ++jj) {
    int k = tg + (jj << 8);
    int mkz = (N2 - k) & (N2 - 1);
    int ik = LP(k), im = LP(N2 - k);
    float akr = Zr[ik],      aki = Zi[ik];
    float bkr = Zr[LP(mkz)], bki = Zi[LP(mkz)];
    float Er  = 0.5f * (akr + bkr);
    float Ei  = 0.5f * (aki - bki);
    float Or_ = 0.5f * (aki + bki);
    float Oi  = 0.5f * (bkr - akr);
    float tr = wc * Or_ - ws * Oi;
    float ti = wc * Oi + ws * Or_;
    float x0r = Er + tr, x0i = Ei + ti;
    float x1r = Er - tr, x1i = ti - Ei;
    Zr[ik] = x0r; Zi[ik] = x0i;
    Zr[im] = x1r; Zi[im] = x1i;
    eb[2 * jj]     = x0r * x0r + x0i * x0i;
    eb[2 * jj + 1] = x1r * x1r + x1i * x1i;
    float nwc = wc * RC - ws * RSn;
    ws = wc * RSn + ws * RC; wc = nwc;
  }
  if (tg == 0) {
    int i4 = LP(1024);
    float re = Zr[i4], im_ = Zi[i4];
    Zi[i4] = -im_;
    eb[8] = re * re + im_ * im_;
  }

  // ---- Selection: tau = max tau s.t. sum(e >= tau) > 0.8*total (per group). ----
  float tloc = 0.0f;
  #pragma unroll
  for (int s = 0; s < 9; ++s) tloc += eb[s];
  float total = group_sum(tloc, redg, tg, 0);
  float thresh = 0.8f * total;

  unsigned lo = 0u, hi = 0x7F7FFFFFu;
  for (int it = 0; it < 31; ++it) {
    unsigned mid = (lo + hi + 1u) >> 1;
    float tau = __uint_as_float(mid);
    float loc = 0.0f;
    #pragma unroll
    for (int s = 0; s < 9; ++s) loc += (eb[s] >= tau) ? eb[s] : 0.0f;
    float ssum = group_sum(loc, redg, tg, (it + 1) & 1);
    if (ssum > thresh) lo = mid; else hi = mid - 1;
  }
  float tau = __uint_as_float(lo);

  // ---- Mask + hermitian repack IN PLACE. ----
  const float RSp = 0.38268343236508977173f;
  __sincosf(PI_F * (float)tg * (1.0f / 2048.0f), &ws, &wc);
  #pragma unroll
  for (int jj = 0; jj < 4; ++jj) {
    int k = tg + (jj << 8);
    int ik = LP(k), im = LP(N2 - k);
    float xkr = Zr[ik], xki = Zi[ik];
    float xmr = Zr[im], xmi = Zi[im];
    float ekk = xkr * xkr + xki * xki;
    float emm = xmr * xmr + xmi * xmi;
    if (ekk >= tau) { xkr = 0.0f; xki = 0.0f; }
    if (emm >= tau) { xmr = 0.0f; xmi = 0.0f; }
    float Er = 0.5f * (xkr + xmr);
    float Ei = 0.5f * (xki - xmi);
    float Br = 0.5f * (xkr - xmr);
    float Bi = 0.5f * (xki + xmi);
    float Or_ = wc * Br - ws * Bi;
    float Oi  = wc * Bi + ws * Br;
    Zr[ik] = Er - Oi;  Zi[ik] = Ei + Or_;
    Zr[im] = Er + Oi;  Zi[im] = Or_ - Ei;
    float nwc = wc * RC - ws * RSp;
    ws = wc * RSp + ws * RC; wc = nwc;
  }
  if (tg == 0) {
    int i4 = LP(1024);
    float re = Zr[i4], im_ = Zi[i4];
    float e = re * re + im_ * im_;
    if (e >= tau) { re = 0.0f; im_ = 0.0f; }
    Zr[i4] = re; Zi[i4] = -im_;
  }
  __syncthreads();

  fft2048<TAB>(Zr, Zi, tg, 1.0f, tab);    // inverse (unscaled); ends with __syncthreads()

  // ---- Store: xvar float4 across the 4 channels; xinv = x - xvar. ----
  // CACHED loads/stores: L2 write-combines the 4 quads' partial-line stores
  // (round-5 lesson: nt here = RMW amplification, 2x writes, +128MB fetches).
  const float scale = 1.0f / 2048.0f;
  size_t base = (size_t)b * (TLEN * CCH) + cbase;
  #pragma unroll
  for (int it = 0; it < 4; ++it) {
    int t = tidx + (it << 10);
    const float* src = &z[t & 1][0][0];
    int k = LP(t >> 1);
    float4 v;
    v.x = src[k]            * scale;
    v.y = src[ZLEN + k]     * scale;
    v.z = src[2 * ZLEN + k] * scale;
    v.w = src[3 * ZLEN + k] * scale;
    size_t off = base + (size_t)t * CCH;
    float4 xv = *(const float4*)(x + off);
    *(float4*)(xvar + off) = v;
    *(float4*)(xinv + off) = make_float4(xv.x - v.x, xv.y - v.y, xv.z - v.z, xv.w - v.w);
  }
}

// Fill twiddle tables (run once per launch; 21KB, L2-resident for the main kernel).
__global__ __launch_bounds__(256) void init_twiddles(float2* __restrict__ tab) {
  int i = blockIdx.x * blockDim.x + threadIdx.x;
  if (i >= TW_COUNT) return;
  float theta;
  if (i < TW_O64) {
    int p = i >> 3, r = i & 7;
    theta = 6.28318530717958647692f * (float)(p * r) * (1.0f / 64.0f);
  } else if (i < TW_O4) {
    int e = i - TW_O64;
    int p = e >> 3, r = e & 7;
    theta = 6.28318530717958647692f * (float)(p * r) * (1.0f / 512.0f);
  } else {
    int e = i - TW_O4;
    int j = e >> 2, r = e & 3;
    theta = PI_F * (float)(j * r) * (1.0f / 1024.0f);
  }
  float sv, cv;
  __sincosf(theta, &sv, &cv);
  tab[i] = make_float2(cv, sv);
}

extern "C" void kernel_launch(void* const* d_in, const int* in_sizes, int n_in,
                              void* d_out, int out_size, void* d_ws, size_t ws_size,
                              hipStream_t stream) {
  const float* x = (const float*)d_in[0];
  float* out  = (float*)d_out;
  float* xvar = out;
  float* xinv = out + HALF;

  if (ws_size >= (size_t)TW_COUNT * sizeof(float2)) {
    float2* tab = (float2*)d_ws;
    init_twiddles<<<(TW_COUNT + 255) / 256, 256, 0, stream>>>(tab);
    fourier_filter_fused<true><<<BB * 32, 1024, 0, stream>>>(x, xvar, xinv, tab);
  } else {
    fourier_filter_fused<false><<<BB * 32, 1024, 0, stream>>>(x, xvar, xinv, nullptr);
  }
}

// Round 8
// 294.800 us; speedup vs baseline: 1.9431x; 1.1455x over previous
//
#include <hip/hip_runtime.h>

// FourierFilter: per-(b,c) rfft-4096 -> top-k (80% energy) spectral mask -> irfft.
// x:[32,4096,128] f32. out = concat(x_var, x_inv), each [32,4096,128].
// SINGLE fused kernel: one 1024-thread block handles 4 ADJACENT channels of one batch
// (4 independent 256-thread FFT "groups" sharing the block's barriers). All global
// traffic is float4 (16B/lane), CACHED (L2 write-combines the 4 sibling blocks'
// partial-line stores; round-5 lesson: nt stores break combining -> RMW, 2x writes).
// Selection: 31-iter bit bisection (constant-time; round-6 lesson: radix-select's
// LDS-atomic hot bins cost 40us). Twiddles: __sincosf chains (HW transcendental,
// ~6 ops; round-7 lesson: table loads spill at the 32-VGPR pin and add latency).
// Round-8 change: store-phase x re-loads hoisted ABOVE the LDS reads (T14) — their
// live range is store-phase-only where pressure is low (r3 lesson: holding them
// across the FFTs spills).
// XCD swizzle keeps the 4 blocks sharing each 64B x/out line dispatch-adjacent on one XCD.

#define TLEN 4096
#define N2   2048
#define CCH  128
#define BB   32
#define HALF 16777216  // 32*4096*128
#define PI_F 3.14159265358979323846f

// LDS pad swizzle for FFT arrays
#define LP(i) ((i) + ((i) >> 5))
#define ZLEN 2113      // LP(2048) + safety

__device__ __forceinline__ void cmul(float& r, float& i, float br, float bi) {
  float tr = r * br - i * bi;
  i = r * bi + i * br;
  r = tr;
}

__device__ __forceinline__ void dft4(float vr[4], float vi[4], float s) {
  float t0r = vr[0] + vr[2], t0i = vi[0] + vi[2];
  float t1r = vr[0] - vr[2], t1i = vi[0] - vi[2];
  float t2r = vr[1] + vr[3], t2i = vi[1] + vi[3];
  float d3r = vr[1] - vr[3], d3i = vi[1] - vi[3];
  float t3r = -s * d3i, t3i = s * d3r;
  vr[0] = t0r + t2r; vi[0] = t0i + t2i;
  vr[1] = t1r + t3r; vi[1] = t1i + t3i;
  vr[2] = t0r - t2r; vi[2] = t0i - t2i;
  vr[3] = t1r - t3r; vi[3] = t1i - t3i;
}

__device__ __forceinline__ void dft8(float vr[8], float vi[8], float s) {
  float er[4]  = {vr[0], vr[2], vr[4], vr[6]};
  float ei[4]  = {vi[0], vi[2], vi[4], vi[6]};
  float odr[4] = {vr[1], vr[3], vr[5], vr[7]};
  float odi[4] = {vi[1], vi[3], vi[5], vi[7]};
  dft4(er, ei, s);
  dft4(odr, odi, s);
  const float c = 0.70710678118654752440f;
  float wr[4] = {1.0f, c, 0.0f, -c};
  float wi[4] = {0.0f, s * c, s, s * c};
  #pragma unroll
  for (int k = 0; k < 4; ++k) {
    float tr = wr[k] * odr[k] - wi[k] * odi[k];
    float ti = wr[k] * odi[k] + wi[k] * odr[k];
    vr[k]     = er[k] + tr; vi[k]     = ei[k] + ti;
    vr[k + 4] = er[k] - tr; vi[k + 4] = ei[k] - ti;
  }
}

__device__ __forceinline__ void stage8_first(float* zr, float* zi, int tid, float s) {
  float vr[8], vi[8];
  #pragma unroll
  for (int r = 0; r < 8; ++r) {
    int idx = LP(tid + (r << 8));
    vr[r] = zr[idx]; vi[r] = zi[idx];
  }
  dft8(vr, vi, s);
  __syncthreads();
  #pragma unroll
  for (int r = 0; r < 8; ++r) {
    int idx = LP((tid << 3) + r);
    zr[idx] = vr[r]; zi[idx] = vi[r];
  }
  __syncthreads();
}

template <int NS>
__device__ __forceinline__ void stage8_tw(float* zr, float* zi, int tid, float s) {
  int j = tid;
  int p = j & (NS - 1);
  float vr[8], vi[8];
  #pragma unroll
  for (int r = 0; r < 8; ++r) {
    int idx = LP(j + (r << 8));
    vr[r] = zr[idx]; vi[r] = zi[idx];
  }
  float ang = s * 6.28318530717958647692f * (float)p / (float)(NS * 8);
  float s1, c1; __sincosf(ang, &s1, &c1);
  float c2 = c1 * c1 - s1 * s1, s2 = 2.0f * c1 * s1;
  float c3 = c2 * c1 - s2 * s1, s3 = c2 * s1 + s2 * c1;
  float c4 = c2 * c2 - s2 * s2, s4 = 2.0f * c2 * s2;
  float c5 = c4 * c1 - s4 * s1, s5 = c4 * s1 + s4 * c1;
  float c6 = c4 * c2 - s4 * s2, s6 = c4 * s2 + s4 * c2;
  float c7 = c4 * c3 - s4 * s3, s7 = c4 * s3 + s4 * c3;
  cmul(vr[1], vi[1], c1, s1);
  cmul(vr[2], vi[2], c2, s2);
  cmul(vr[3], vi[3], c3, s3);
  cmul(vr[4], vi[4], c4, s4);
  cmul(vr[5], vi[5], c5, s5);
  cmul(vr[6], vi[6], c6, s6);
  cmul(vr[7], vi[7], c7, s7);
  dft8(vr, vi, s);
  __syncthreads();
  int idxD = ((j - p) << 3) + p;
  #pragma unroll
  for (int r = 0; r < 8; ++r) {
    int idx = LP(idxD + r * NS);
    zr[idx] = vr[r]; zi[idx] = vi[r];
  }
  __syncthreads();
}

__device__ __forceinline__ void stage4_last(float* zr, float* zi, int tid, float s) {
  #pragma unroll
  for (int half = 0; half < 2; ++half) {
    int j = tid + (half << 8);
    float ang = s * PI_F * (float)j * (1.0f / 1024.0f);
    float s1, c1; __sincosf(ang, &s1, &c1);
    float c2 = c1 * c1 - s1 * s1, s2 = 2.0f * c1 * s1;
    float c3 = c2 * c1 - s2 * s1, s3 = c2 * s1 + s2 * c1;
    float vr[4], vi[4];
    #pragma unroll
    for (int r = 0; r < 4; ++r) {
      int idx = LP(j + (r << 9));
      vr[r] = zr[idx]; vi[r] = zi[idx];
    }
    cmul(vr[1], vi[1], c1, s1);
    cmul(vr[2], vi[2], c2, s2);
    cmul(vr[3], vi[3], c3, s3);
    dft4(vr, vi, s);
    #pragma unroll
    for (int r = 0; r < 4; ++r) {
      int idx = LP(j + (r << 9));
      zr[idx] = vr[r]; zi[idx] = vi[r];
    }
  }
  __syncthreads();
}

__device__ __forceinline__ void fft2048(float* zr, float* zi, int tid, float s) {
  stage8_first(zr, zi, tid, s);
  stage8_tw<8>(zr, zi, tid, s);
  stage8_tw<64>(zr, zi, tid, s);
  stage4_last(zr, zi, tid, s);
}

// Group-level (256-thread) reduction inside a 1024-thread block; all threads call it.
__device__ __forceinline__ float group_sum(float v, float* redg, int tg, int bank) {
  #pragma unroll
  for (int o = 32; o > 0; o >>= 1) v += __shfl_down(v, o, 64);
  if ((tg & 63) == 0) redg[(bank << 2) + (tg >> 6)] = v;
  __syncthreads();
  int b4 = bank << 2;
  return redg[b4] + redg[b4 + 1] + redg[b4 + 2] + redg[b4 + 3];
}

// One 1024-thread block per (batch b, channel-quad cg): 4 independent FFT groups.
__global__ __launch_bounds__(1024, 8) void fourier_filter_fused(const float* __restrict__ x,
                                                                float* __restrict__ xvar,
                                                                float* __restrict__ xinv) {
  // z[0]=real planes, z[1]=imag planes; plane g = series for channel cbase+g.
  __shared__ float z[2][4][ZLEN];
  __shared__ float red[64];   // 8 floats per group (2 banks x 4 waves), 4 groups

  int tidx = threadIdx.x;

  // XCD swizzle: bid = m*8 + r round-robins r across XCDs. Decompose m so the 4
  // blocks sharing each 64B line (same b, same line-group, ql=0..3) are
  // m-consecutive on the same XCD r, and the line-group rotates with (r+b).
  int bid = blockIdx.x;
  int r = bid & 7;            // XCD under round-robin dispatch
  int m = bid >> 3;           // 0..127
  int b = m >> 2;             // 0..31
  int ql = m & 3;             // quad-within-line-group
  int cg = (((r + b) & 7) << 2) | ql;   // channel-quad 0..31
  int cbase = cg << 2;

  const float* xp = x + (size_t)b * (TLEN * CCH) + cbase;

  // ---- Load: thread covers time t; float4 spans the block's 4 channels. ----
  // (Do NOT hold x in registers across the FFTs: at the 32-VGPR pin that spills —
  //  round-3 lesson, +176MB scratch traffic. Re-read at store time instead.)
  #pragma unroll
  for (int it = 0; it < 4; ++it) {
    int t = tidx + (it << 10);
    float4 v = *(const float4*)(xp + (size_t)t * CCH);
    float* dst = &z[t & 1][0][0];       // parity -> real/imag plane (no branch)
    int k = LP(t >> 1);
    dst[k]            = v.x;
    dst[ZLEN + k]     = v.y;
    dst[2 * ZLEN + k] = v.z;
    dst[3 * ZLEN + k] = v.w;
  }
  __syncthreads();

  int g  = tidx >> 8;         // FFT group = channel within quad
  int tg = tidx & 255;        // thread-in-group
  float* Zr = z[0][g];
  float* Zi = z[1][g];
  float* redg = red + (g << 3);

  fft2048(Zr, Zi, tg, -1.0f);   // forward

  // ---- Unpack to rfft bins X[0..2048] IN PLACE; energies in regs. ----
  float eb[9];
  eb[8] = 0.0f;
  const float RC  = 0.92387953251128675613f;   // cos(pi/8)
  const float RSn = -0.38268343236508977173f;  // -sin(pi/8)
  float ws, wc;
  __sincosf(-PI_F * (float)tg * (1.0f / 2048.0f), &ws, &wc);
  #pragma unroll
  for (int jj = 0; jj < 4; ++jj) {
    int k = tg + (jj << 8);
    int mkz = (N2 - k) & (N2 - 1);
    int ik = LP(k), im = LP(N2 - k);
    float akr = Zr[ik],      aki = Zi[ik];
    float bkr = Zr[LP(mkz)], bki = Zi[LP(mkz)];
    float Er  = 0.5f * (akr + bkr);
    float Ei  = 0.5f * (aki - bki);
    float Or_ = 0.5f * (aki + bki);
    float Oi  = 0.5f * (bkr - akr);
    float tr = wc * Or_ - ws * Oi;
    float ti = wc * Oi + ws * Or_;
    float x0r = Er + tr, x0i = Ei + ti;
    float x1r = Er - tr, x1i = ti - Ei;
    Zr[ik] = x0r; Zi[ik] = x0i;
    Zr[im] = x1r; Zi[im] = x1i;
    eb[2 * jj]     = x0r * x0r + x0i * x0i;
    eb[2 * jj + 1] = x1r * x1r + x1i * x1i;
    float nwc = wc * RC - ws * RSn;
    ws = wc * RSn + ws * RC; wc = nwc;
  }
  if (tg == 0) {
    int i4 = LP(1024);
    float re = Zr[i4], im_ = Zi[i4];
    Zi[i4] = -im_;
    eb[8] = re * re + im_ * im_;
  }

  // ---- Selection: tau = max tau s.t. sum(e >= tau) > 0.8*total (per group). ----
  float tloc = 0.0f;
  #pragma unroll
  for (int s = 0; s < 9; ++s) tloc += eb[s];
  float total = group_sum(tloc, redg, tg, 0);
  float thresh = 0.8f * total;

  unsigned lo = 0u, hi = 0x7F7FFFFFu;
  for (int it = 0; it < 31; ++it) {
    unsigned mid = (lo + hi + 1u) >> 1;
    float tau = __uint_as_float(mid);
    float loc = 0.0f;
    #pragma unroll
    for (int s = 0; s < 9; ++s) loc += (eb[s] >= tau) ? eb[s] : 0.0f;
    float ssum = group_sum(loc, redg, tg, (it + 1) & 1);
    if (ssum > thresh) lo = mid; else hi = mid - 1;
  }
  float tau = __uint_as_float(lo);

  // ---- Mask + hermitian repack IN PLACE. ----
  const float RSp = 0.38268343236508977173f;
  __sincosf(PI_F * (float)tg * (1.0f / 2048.0f), &ws, &wc);
  #pragma unroll
  for (int jj = 0; jj < 4; ++jj) {
    int k = tg + (jj << 8);
    int ik = LP(k), im = LP(N2 - k);
    float xkr = Zr[ik], xki = Zi[ik];
    float xmr = Zr[im], xmi = Zi[im];
    float ekk = xkr * xkr + xki * xki;
    float emm = xmr * xmr + xmi * xmi;
    if (ekk >= tau) { xkr = 0.0f; xki = 0.0f; }
    if (emm >= tau) { xmr = 0.0f; xmi = 0.0f; }
    float Er = 0.5f * (xkr + xmr);
    float Ei = 0.5f * (xki - xmi);
    float Br = 0.5f * (xkr - xmr);
    float Bi = 0.5f * (xki + xmi);
    float Or_ = wc * Br - ws * Bi;
    float Oi  = wc * Bi + ws * Br;
    Zr[ik] = Er - Oi;  Zi[ik] = Ei + Or_;
    Zr[im] = Er + Oi;  Zi[im] = Or_ - Ei;
    float nwc = wc * RC - ws * RSp;
    ws = wc * RSp + ws * RC; wc = nwc;
  }
  if (tg == 0) {
    int i4 = LP(1024);
    float re = Zr[i4], im_ = Zi[i4];
    float e = re * re + im_ * im_;
    if (e >= tau) { re = 0.0f; im_ = 0.0f; }
    Zr[i4] = re; Zi[i4] = -im_;
  }
  __syncthreads();

  fft2048(Zr, Zi, tg, 1.0f);    // inverse (unscaled); ends with __syncthreads()

  // ---- Store: xvar float4 across the 4 channels; xinv = x - xvar. ----
  // CACHED loads/stores (round-5 lesson: nt breaks L2 write-combining -> RMW).
  // T14 hoist: issue all 4 x re-loads BEFORE the LDS reads; their ~600-cycle
  // latency hides under the 4 iterations of LDS reads + scaling. Live range is
  // store-phase-only, so no FFT-phase register pressure (r3/r7 spill lesson).
  const float scale = 1.0f / 2048.0f;
  size_t base = (size_t)b * (TLEN * CCH) + cbase;
  float4 xv[4];
  #pragma unroll
  for (int it = 0; it < 4; ++it) {
    int t = tidx + (it << 10);
    xv[it] = *(const float4*)(x + base + (size_t)t * CCH);
  }
  #pragma unroll
  for (int it = 0; it < 4; ++it) {
    int t = tidx + (it << 10);
    const float* src = &z[t & 1][0][0];
    int k = LP(t >> 1);
    float4 v;
    v.x = src[k]            * scale;
    v.y = src[ZLEN + k]     * scale;
    v.z = src[2 * ZLEN + k] * scale;
    v.w = src[3 * ZLEN + k] * scale;
    size_t off = base + (size_t)t * CCH;
    *(float4*)(xvar + off) = v;
    *(float4*)(xinv + off) = make_float4(xv[it].x - v.x, xv[it].y - v.y,
                                         xv[it].z - v.z, xv[it].w - v.w);
  }
}

extern "C" void kernel_launch(void* const* d_in, const int* in_sizes, int n_in,
                              void* d_out, int out_size, void* d_ws, size_t ws_size,
                              hipStream_t stream) {
  const float* x = (const float*)d_in[0];
  float* out  = (float*)d_out;
  float* xvar = out;
  float* xinv = out + HALF;

  (void)d_ws; (void)ws_size;
  fourier_filter_fused<<<BB * 32, 1024, 0, stream>>>(x, xvar, xinv);
}